// Round 1
// baseline (1276.400 us; speedup 1.0000x reference)
//
#include <hip/hip_runtime.h>
#include <math.h>

namespace {
constexpr int Bc = 4, Lc = 1024, Dc = 768, Hc = 12, HDc = 64;
constexpr int MAXL = 1024;
}

// ---------------- GEMM: out[M,768] = A[M,768] @ W[768,768] + bias ----------
// headmajor=1: out layout [B,H,L,64] (for q/k/v); headmajor=0: plain [M,768].
__global__ __launch_bounds__(256) void gemm64(
    const float* __restrict__ A,
    const float* __restrict__ W0, const float* __restrict__ W1, const float* __restrict__ W2,
    const float* __restrict__ b0, const float* __restrict__ b1, const float* __restrict__ b2,
    float* __restrict__ o0, float* __restrict__ o1, float* __restrict__ o2,
    int headmajor)
{
    const float* W; const float* bias; float* out;
    if (blockIdx.z == 0)      { W = W0; bias = b0; out = o0; }
    else if (blockIdx.z == 1) { W = W1; bias = b1; out = o1; }
    else                      { W = W2; bias = b2; out = o2; }

    const int K = Dc;
    const int n0 = blockIdx.x * 64;
    const int m0 = blockIdx.y * 64;

    __shared__ float As[16][64];   // transposed: As[k][m]
    __shared__ float Bs[16][64];   // Bs[k][n]

    const int tid = threadIdx.x;
    const int tx = tid & 15, ty = tid >> 4;
    const int arow = tid >> 2, aq = (tid & 3) * 4;
    const int brow = tid >> 4, bq4 = (tid & 15) * 4;

    float acc[4][4] = {};

    for (int k0 = 0; k0 < K; k0 += 16) {
        float4 av = *(const float4*)&A[(size_t)(m0 + arow) * K + k0 + aq];
        float4 bv = *(const float4*)&W[(size_t)(k0 + brow) * Dc + n0 + bq4];
        __syncthreads();
        As[aq + 0][arow] = av.x;
        As[aq + 1][arow] = av.y;
        As[aq + 2][arow] = av.z;
        As[aq + 3][arow] = av.w;
        *(float4*)&Bs[brow][bq4] = bv;
        __syncthreads();
#pragma unroll
        for (int kk = 0; kk < 16; ++kk) {
            float4 a = *(const float4*)&As[kk][ty * 4];
            float4 b = *(const float4*)&Bs[kk][tx * 4];
            acc[0][0] += a.x * b.x; acc[0][1] += a.x * b.y; acc[0][2] += a.x * b.z; acc[0][3] += a.x * b.w;
            acc[1][0] += a.y * b.x; acc[1][1] += a.y * b.y; acc[1][2] += a.y * b.z; acc[1][3] += a.y * b.w;
            acc[2][0] += a.z * b.x; acc[2][1] += a.z * b.y; acc[2][2] += a.z * b.z; acc[2][3] += a.z * b.w;
            acc[3][0] += a.w * b.x; acc[3][1] += a.w * b.y; acc[3][2] += a.w * b.z; acc[3][3] += a.w * b.w;
        }
    }

    float4 bb = *(const float4*)&bias[n0 + tx * 4];
    if (!headmajor) {
#pragma unroll
        for (int i = 0; i < 4; ++i) {
            int m = m0 + ty * 4 + i;
            float4 c;
            c.x = acc[i][0] + bb.x; c.y = acc[i][1] + bb.y;
            c.z = acc[i][2] + bb.z; c.w = acc[i][3] + bb.w;
            *(float4*)&out[(size_t)m * Dc + n0 + tx * 4] = c;
        }
    } else {
        const int h = n0 >> 6;   // tile N width 64 == head dim
#pragma unroll
        for (int i = 0; i < 4; ++i) {
            int m = m0 + ty * 4 + i;
            int bI = m >> 10, l = m & 1023;
            float4 c;
            c.x = acc[i][0] + bb.x; c.y = acc[i][1] + bb.y;
            c.z = acc[i][2] + bb.z; c.w = acc[i][3] + bb.w;
            *(float4*)&out[(((size_t)bI * Hc + h) * Lc + l) * HDc + tx * 4] = c;
        }
    }
}

// ---------------- Fused relative-position attention ------------------------
// grid (L/16, H, B), 256 threads. Per block: 16 query rows, online softmax
// over key tiles of 64. scores[l][r] = (q_l.k_r + (q_l+k_r).E[l-r+1023]) / 8
__global__ __launch_bounds__(256) void attn_k(
    const float* __restrict__ qg, const float* __restrict__ kg,
    const float* __restrict__ vg, const float* __restrict__ Eg,
    float* __restrict__ ctx)
{
    const int b = blockIdx.z, h = blockIdx.y;
    const int l0 = blockIdx.x * 16;
    const size_t bh = (size_t)(b * Hc + h) * Lc * HDc;
    const float* qh = qg + bh;
    const float* kh = kg + bh;
    const float* vh = vg + bh;

    __shared__ float sQ[16][64];
    __shared__ float sK[64][65];   // pad 65: conflict-free lane-strided row reads
    __shared__ float sV[64][64];
    __shared__ float sE[79][65];   // E band, rows j-jbase for j=l-r+1023
    __shared__ float sS[16][64];   // score/prob tile
    __shared__ float sm_m[16], sm_l[16], sm_sc[16];

    const int tid = threadIdx.x;
    const int lane = tid & 63;
    const int wv = tid >> 6;

    {
        int r = tid >> 4, c4 = (tid & 15) * 4;
        *(float4*)&sQ[r][c4] = *(const float4*)&qh[(size_t)(l0 + r) * 64 + c4];
    }
    if (tid < 16) { sm_m[tid] = -INFINITY; sm_l[tid] = 0.0f; }

    float cacc[4] = {0.f, 0.f, 0.f, 0.f};

    for (int r0 = 0; r0 < Lc; r0 += 64) {
        __syncthreads();   // previous tile fully consumed
        // ---- stage K and V tiles
#pragma unroll
        for (int i = 0; i < 4; ++i) {
            int idx = tid + i * 256;
            int r = idx >> 4, c4 = (idx & 15) * 4;
            float4 kv = *(const float4*)&kh[(size_t)(r0 + r) * 64 + c4];
            sK[r][c4 + 0] = kv.x; sK[r][c4 + 1] = kv.y;
            sK[r][c4 + 2] = kv.z; sK[r][c4 + 3] = kv.w;
            *(float4*)&sV[r][c4] = *(const float4*)&vh[(size_t)(r0 + r) * 64 + c4];
        }
        // ---- stage E band: rows jbase .. jbase+78, always within [0,2046]
        const int jbase = l0 - r0 + (MAXL - 64);
        for (int idx4 = tid; idx4 < 79 * 16; idx4 += 256) {
            int e = idx4 >> 4, c4 = (idx4 & 15) * 4;
            float4 ev = *(const float4*)&Eg[(size_t)(jbase + e) * 64 + c4];
            sE[e][c4 + 0] = ev.x; sE[e][c4 + 1] = ev.y;
            sE[e][c4 + 2] = ev.z; sE[e][c4 + 3] = ev.w;
        }
        __syncthreads();
        // ---- scores: thread owns dr=lane, rows dl = wv+4i
        {
            const int dr = lane;
            const float* kp  = &sK[dr][0];
            const float* qp0 = &sQ[wv][0];
            const float* qp1 = &sQ[wv + 4][0];
            const float* qp2 = &sQ[wv + 8][0];
            const float* qp3 = &sQ[wv + 12][0];
            const float* ep0 = &sE[wv + 63 - dr][0];
            const float* ep1 = &sE[wv + 4 + 63 - dr][0];
            const float* ep2 = &sE[wv + 8 + 63 - dr][0];
            const float* ep3 = &sE[wv + 12 + 63 - dr][0];
            float a0 = 0.f, a1 = 0.f, a2 = 0.f, a3 = 0.f;
            for (int d = 0; d < 64; ++d) {
                float kd = kp[d];
                float q0 = qp0[d], q1 = qp1[d], q2 = qp2[d], q3 = qp3[d];
                a0 += q0 * kd + (q0 + kd) * ep0[d];
                a1 += q1 * kd + (q1 + kd) * ep1[d];
                a2 += q2 * kd + (q2 + kd) * ep2[d];
                a3 += q3 * kd + (q3 + kd) * ep3[d];
            }
            sS[wv][dr]      = a0 * 0.125f;
            sS[wv + 4][dr]  = a1 * 0.125f;
            sS[wv + 8][dr]  = a2 * 0.125f;
            sS[wv + 12][dr] = a3 * 0.125f;
        }
        __syncthreads();
        // ---- online softmax: wave wv owns rows wv*4..wv*4+3
#pragma unroll
        for (int rr = 0; rr < 4; ++rr) {
            int row = wv * 4 + rr;
            float sv = sS[row][lane];
            float mx = sv;
            for (int off = 32; off > 0; off >>= 1) mx = fmaxf(mx, __shfl_xor(mx, off));
            float mold = sm_m[row];
            float mnew = fmaxf(mold, mx);
            float p = expf(sv - mnew);
            float su = p;
            for (int off = 32; off > 0; off >>= 1) su += __shfl_xor(su, off);
            sS[row][lane] = p;
            if (lane == 0) {
                float sc = expf(mold - mnew);   // 0 on first tile (mold=-inf)
                sm_sc[row] = sc;
                sm_l[row] = sm_l[row] * sc + su;
                sm_m[row] = mnew;
            }
        }
        __syncthreads();
        // ---- PV accumulate: thread owns col=lane, rows dl = wv+4i
#pragma unroll
        for (int i = 0; i < 4; ++i) {
            int dl = wv + 4 * i;
            float a = cacc[i] * sm_sc[dl];
            const float* pp = &sS[dl][0];
            const float* vp = &sV[0][0] + lane;
            for (int dr = 0; dr < 64; ++dr) a += pp[dr] * vp[dr * 64];
            cacc[i] = a;
        }
    }
    __syncthreads();
#pragma unroll
    for (int i = 0; i < 4; ++i) {
        int dl = wv + 4 * i;
        float o = cacc[i] / sm_l[dl];
        // ctx layout [B*L, 768] row-major, col = h*64+lane
        ctx[((size_t)(b * Lc + l0 + dl)) * Dc + h * HDc + lane] = o;
    }
}

extern "C" void kernel_launch(void* const* d_in, const int* in_sizes, int n_in,
                              void* d_out, int out_size, void* d_ws, size_t ws_size,
                              hipStream_t stream) {
    const float* hs = (const float*)d_in[0];
    const float* Wq = (const float*)d_in[1];
    const float* bq = (const float*)d_in[2];
    const float* Wk = (const float*)d_in[3];
    const float* bk = (const float*)d_in[4];
    const float* Wv = (const float*)d_in[5];
    const float* bv = (const float*)d_in[6];
    const float* Wd = (const float*)d_in[7];
    const float* bd = (const float*)d_in[8];
    const float* Eg = (const float*)d_in[9];

    const size_t NELEM = (size_t)Bc * Lc * Dc;   // 3,145,728
    float* q   = (float*)d_ws;
    float* k   = q + NELEM;
    float* v   = k + NELEM;
    float* ctx = v + NELEM;

    dim3 blk(256);
    // QKV projection (head-major outputs)
    gemm64<<<dim3(12, 64, 3), blk, 0, stream>>>(hs, Wq, Wk, Wv, bq, bk, bv, q, k, v, 1);
    // fused relative-position attention
    attn_k<<<dim3(Lc / 16, Hc, Bc), blk, 0, stream>>>(q, k, v, Eg, ctx);
    // output projection
    gemm64<<<dim3(12, 64, 1), blk, 0, stream>>>(ctx, Wd, Wd, Wd, bd, bd, bd,
                                                (float*)d_out, (float*)d_out, (float*)d_out, 0);
}

// Round 2
// 511.327 us; speedup vs baseline: 2.4963x; 2.4963x over previous
//
#include <hip/hip_runtime.h>
#include <hip/hip_bf16.h>
#include <math.h>

typedef __bf16 bf16x8 __attribute__((ext_vector_type(8)));
typedef float f32x4 __attribute__((ext_vector_type(4)));

namespace {
constexpr int Bc = 4, Lc = 1024, Dc = 768, Hc = 12, HDc = 64;
}

static __device__ __forceinline__ ushort f2bf(float f) {
    __hip_bfloat16 h = __float2bfloat16(f);
    return *reinterpret_cast<ushort*>(&h);
}
static __device__ __forceinline__ float bf2f(ushort u) {
    __hip_bfloat16 h;
    *reinterpret_cast<ushort*>(&h) = u;
    return __bfloat162float(h);
}

// ---------------- fp32 -> bf16 convert (dist_emb) --------------------------
__global__ void cvt_bf16_k(const float* __restrict__ in, ushort* __restrict__ out, int n) {
    int i = blockIdx.x * 256 + threadIdx.x;
    if (i < n) out[i] = f2bf(in[i]);
}

// ---------------- GEMM: out[M,768] = A[M,768] @ W[768,768] + bias ----------
// BF16HM=1: bf16 output in head-major [B,H,L,64]; BF16HM=0: fp32 plain [M,768].
template <int BF16HM>
__global__ __launch_bounds__(256) void gemm64(
    const float* __restrict__ A,
    const float* __restrict__ W0, const float* __restrict__ W1, const float* __restrict__ W2,
    const float* __restrict__ b0, const float* __restrict__ b1, const float* __restrict__ b2,
    void* o0, void* o1, void* o2)
{
    const float* W; const float* bias; void* outv;
    if (blockIdx.z == 0)      { W = W0; bias = b0; outv = o0; }
    else if (blockIdx.z == 1) { W = W1; bias = b1; outv = o1; }
    else                      { W = W2; bias = b2; outv = o2; }

    const int K = Dc;
    const int n0 = blockIdx.x * 64;
    const int m0 = blockIdx.y * 64;

    __shared__ float As[16][64];
    __shared__ float Bs[16][64];

    const int tid = threadIdx.x;
    const int tx = tid & 15, ty = tid >> 4;
    const int arow = tid >> 2, aq = (tid & 3) * 4;
    const int brow = tid >> 4, bq4 = (tid & 15) * 4;

    float acc[4][4] = {};

    for (int k0 = 0; k0 < K; k0 += 16) {
        float4 av = *(const float4*)&A[(size_t)(m0 + arow) * K + k0 + aq];
        float4 bv = *(const float4*)&W[(size_t)(k0 + brow) * Dc + n0 + bq4];
        __syncthreads();
        As[aq + 0][arow] = av.x;
        As[aq + 1][arow] = av.y;
        As[aq + 2][arow] = av.z;
        As[aq + 3][arow] = av.w;
        *(float4*)&Bs[brow][bq4] = bv;
        __syncthreads();
#pragma unroll
        for (int kk = 0; kk < 16; ++kk) {
            float4 a = *(const float4*)&As[kk][ty * 4];
            float4 b = *(const float4*)&Bs[kk][tx * 4];
            acc[0][0] += a.x * b.x; acc[0][1] += a.x * b.y; acc[0][2] += a.x * b.z; acc[0][3] += a.x * b.w;
            acc[1][0] += a.y * b.x; acc[1][1] += a.y * b.y; acc[1][2] += a.y * b.z; acc[1][3] += a.y * b.w;
            acc[2][0] += a.z * b.x; acc[2][1] += a.z * b.y; acc[2][2] += a.z * b.z; acc[2][3] += a.z * b.w;
            acc[3][0] += a.w * b.x; acc[3][1] += a.w * b.y; acc[3][2] += a.w * b.z; acc[3][3] += a.w * b.w;
        }
    }

    float4 bb = *(const float4*)&bias[n0 + tx * 4];
    if (BF16HM == 0) {
        float* out = (float*)outv;
#pragma unroll
        for (int i = 0; i < 4; ++i) {
            int m = m0 + ty * 4 + i;
            float4 c;
            c.x = acc[i][0] + bb.x; c.y = acc[i][1] + bb.y;
            c.z = acc[i][2] + bb.z; c.w = acc[i][3] + bb.w;
            *(float4*)&out[(size_t)m * Dc + n0 + tx * 4] = c;
        }
    } else {
        ushort* out = (ushort*)outv;
        const int h = n0 >> 6;
#pragma unroll
        for (int i = 0; i < 4; ++i) {
            int m = m0 + ty * 4 + i;
            int bI = m >> 10, l = m & 1023;
            ushort4 c;
            c.x = f2bf(acc[i][0] + bb.x); c.y = f2bf(acc[i][1] + bb.y);
            c.z = f2bf(acc[i][2] + bb.z); c.w = f2bf(acc[i][3] + bb.w);
            *(ushort4*)&out[(((size_t)bI * Hc + h) * Lc + l) * HDc + tx * 4] = c;
        }
    }
}

// ---------------- Fused relative-position attention (MFMA) -----------------
// grid (16, H, B), 256 threads = 4 waves. Block owns 64 query rows of (b,h).
// scores[l][r] = (q_l.k_r + q_l.E_j + k_r.E_j)/8,  j = l-r+1023.
// Per 64-key tile: E band rows jb..jb+126 (jb = l0-r0+960), always in-bounds.
__global__ __launch_bounds__(256, 2) void attn_mfma(
    const ushort* __restrict__ qg, const ushort* __restrict__ kg,
    const ushort* __restrict__ vg, const ushort* __restrict__ Eb,
    float* __restrict__ ctx)
{
    const int b = blockIdx.z, h = blockIdx.y;
    const int l0 = blockIdx.x * 64;
    const size_t bh = (size_t)(b * Hc + h) * Lc * HDc;
    const ushort* qh = qg + bh;
    const ushort* kh = kg + bh;
    const ushort* vh = vg + bh;

    __shared__ ushort sK[64][72];       //  9216 B  K tile row-major
    __shared__ ushort sVt[64][72];      //  9216 B  V tile transposed [dim][key]
    __shared__ ushort sEP[128 * 72];    // 18432 B  E band (phase B) / P probs (phase C/D)
    __shared__ ushort sQE[64][132];     // 16896 B  QE^T gather table [qrow][jcol]
    __shared__ ushort sKE[64][132];     // 16896 B  KE^T gather table [krow][jcol]

    const int tid = threadIdx.x;
    const int lane = tid & 63;
    const int w = tid >> 6;        // wave 0..3, owns q-strip rows 16w..16w+15
    const int g = lane >> 4;       // 0..3
    const int r = lane & 15;       // 0..15

    // Q A-frags, resident in regs for the whole K loop:
    // frag kk elem i = Q[l0+16w+r][kk*32 + g*8 + i]
    bf16x8 qf0, qf1;
    {
        const ushort* qrow = qh + (size_t)(l0 + 16 * w + r) * 64;
        qf0 = *reinterpret_cast<const bf16x8*>(qrow + g * 8);
        qf1 = *reinterpret_cast<const bf16x8*>(qrow + 32 + g * 8);
    }

    f32x4 cacc[4];
#pragma unroll
    for (int cf = 0; cf < 4; ++cf) cacc[cf] = (f32x4){0.f, 0.f, 0.f, 0.f};
    float mrun[4], lrun[4];
#pragma unroll
    for (int i = 0; i < 4; ++i) { mrun[i] = -1e30f; lrun[i] = 0.f; }

    for (int r0 = 0; r0 < Lc; r0 += 64) {
        __syncthreads();   // previous iter fully consumed
        // ---- phase A: stage K, Vt, E band
#pragma unroll
        for (int c = tid; c < 512; c += 256) {
            int row = c >> 3, seg = c & 7;
            *reinterpret_cast<uint4*>(&sK[row][seg * 8]) =
                *reinterpret_cast<const uint4*>(kh + (size_t)(r0 + row) * 64 + seg * 8);
        }
        {
            int row = tid & 63, dseg = tid >> 6;
            const ushort* vrow = vh + (size_t)(r0 + row) * 64 + dseg * 16;
            uint4 a0 = *reinterpret_cast<const uint4*>(vrow);
            uint4 a1 = *reinterpret_cast<const uint4*>(vrow + 8);
            const ushort* t0 = reinterpret_cast<const ushort*>(&a0);
            const ushort* t1 = reinterpret_cast<const ushort*>(&a1);
#pragma unroll
            for (int j = 0; j < 8; ++j) sVt[dseg * 16 + j][row] = t0[j];
#pragma unroll
            for (int j = 0; j < 8; ++j) sVt[dseg * 16 + 8 + j][row] = t1[j];
        }
        const int jb = l0 - r0 + 960;   // in [0,1920]; rows jb..jb+126 valid
#pragma unroll
        for (int c = tid; c < 1024; c += 256) {
            int row = c >> 3, seg = c & 7;
            uint4 val;
            if (row < 127)
                val = *reinterpret_cast<const uint4*>(Eb + (size_t)(jb + row) * 64 + seg * 8);
            else
                val = make_uint4(0, 0, 0, 0);   // col 127 never gathered; keep finite
            *reinterpret_cast<uint4*>(&sEP[row * 72 + seg * 8]) = val;
        }
        __syncthreads();

        // ---- phase B: QK^T, QE^T, KE^T via MFMA
        f32x4 S[4];
#pragma unroll
        for (int cf = 0; cf < 4; ++cf) {
            f32x4 acc = (f32x4){0.f, 0.f, 0.f, 0.f};
            bf16x8 kf0 = *reinterpret_cast<const bf16x8*>(&sK[16 * cf + r][g * 8]);
            bf16x8 kf1 = *reinterpret_cast<const bf16x8*>(&sK[16 * cf + r][32 + g * 8]);
            acc = __builtin_amdgcn_mfma_f32_16x16x32_bf16(qf0, kf0, acc, 0, 0, 0);
            acc = __builtin_amdgcn_mfma_f32_16x16x32_bf16(qf1, kf1, acc, 0, 0, 0);
            S[cf] = acc;
        }
        bf16x8 kaf0 = *reinterpret_cast<const bf16x8*>(&sK[16 * w + r][g * 8]);
        bf16x8 kaf1 = *reinterpret_cast<const bf16x8*>(&sK[16 * w + r][32 + g * 8]);
#pragma unroll
        for (int cf = 0; cf < 8; ++cf) {
            bf16x8 ef0 = *reinterpret_cast<const bf16x8*>(&sEP[(16 * cf + r) * 72 + g * 8]);
            bf16x8 ef1 = *reinterpret_cast<const bf16x8*>(&sEP[(16 * cf + r) * 72 + 32 + g * 8]);
            f32x4 aq = (f32x4){0.f, 0.f, 0.f, 0.f};
            f32x4 ak = (f32x4){0.f, 0.f, 0.f, 0.f};
            aq = __builtin_amdgcn_mfma_f32_16x16x32_bf16(qf0, ef0, aq, 0, 0, 0);
            aq = __builtin_amdgcn_mfma_f32_16x16x32_bf16(qf1, ef1, aq, 0, 0, 0);
            ak = __builtin_amdgcn_mfma_f32_16x16x32_bf16(kaf0, ef0, ak, 0, 0, 0);
            ak = __builtin_amdgcn_mfma_f32_16x16x32_bf16(kaf1, ef1, ak, 0, 0, 0);
#pragma unroll
            for (int i = 0; i < 4; ++i) {
                sQE[16 * w + 4 * g + i][16 * cf + r] = f2bf(aq[i]);
                sKE[16 * w + 4 * g + i][16 * cf + r] = f2bf(ak[i]);
            }
        }
        __syncthreads();

        // ---- phase C: assemble S + online softmax (C-frag layout)
        float p[4][4];   // [col-group][row]
#pragma unroll
        for (int cf = 0; cf < 4; ++cf) {
#pragma unroll
            for (int i = 0; i < 4; ++i) {
                int qr = 16 * w + 4 * g + i;     // q row in tile
                int kc = 16 * cf + r;            // key col in tile
                int col = qr - kc + 63;          // 0..126
                p[cf][i] = (S[cf][i] + bf2f(sQE[qr][col]) + bf2f(sKE[kc][col])) * 0.125f;
            }
        }
#pragma unroll
        for (int i = 0; i < 4; ++i) {
            float m0 = fmaxf(fmaxf(p[0][i], p[1][i]), fmaxf(p[2][i], p[3][i]));
#pragma unroll
            for (int off = 1; off < 16; off <<= 1) m0 = fmaxf(m0, __shfl_xor(m0, off));
            float mn = fmaxf(mrun[i], m0);
            float sc = __expf(mrun[i] - mn);
            mrun[i] = mn;
            float rsum = 0.f;
#pragma unroll
            for (int cf = 0; cf < 4; ++cf) {
                float e = __expf(p[cf][i] - mn);
                p[cf][i] = e;
                rsum += e;
            }
#pragma unroll
            for (int off = 1; off < 16; off <<= 1) rsum += __shfl_xor(rsum, off);
            lrun[i] = lrun[i] * sc + rsum;
#pragma unroll
            for (int cf = 0; cf < 4; ++cf) cacc[cf][i] *= sc;
        }
        // write P (bf16) into sEP region (E already consumed)
#pragma unroll
        for (int cf = 0; cf < 4; ++cf)
#pragma unroll
            for (int i = 0; i < 4; ++i)
                sEP[(16 * w + 4 * g + i) * 72 + 16 * cf + r] = f2bf(p[cf][i]);
        __syncthreads();

        // ---- phase D: PV
        bf16x8 pf0 = *reinterpret_cast<const bf16x8*>(&sEP[(16 * w + r) * 72 + g * 8]);
        bf16x8 pf1 = *reinterpret_cast<const bf16x8*>(&sEP[(16 * w + r) * 72 + 32 + g * 8]);
#pragma unroll
        for (int cf = 0; cf < 4; ++cf) {
            bf16x8 vf0 = *reinterpret_cast<const bf16x8*>(&sVt[16 * cf + r][g * 8]);
            bf16x8 vf1 = *reinterpret_cast<const bf16x8*>(&sVt[16 * cf + r][32 + g * 8]);
            cacc[cf] = __builtin_amdgcn_mfma_f32_16x16x32_bf16(pf0, vf0, cacc[cf], 0, 0, 0);
            cacc[cf] = __builtin_amdgcn_mfma_f32_16x16x32_bf16(pf1, vf1, cacc[cf], 0, 0, 0);
        }
    }

    // ---- epilogue: normalize and write ctx fp32 [B*L, 768]
    float rinv[4];
#pragma unroll
    for (int i = 0; i < 4; ++i) rinv[i] = 1.0f / lrun[i];
#pragma unroll
    for (int cf = 0; cf < 4; ++cf) {
#pragma unroll
        for (int i = 0; i < 4; ++i) {
            int qr = 16 * w + 4 * g + i;
            ctx[((size_t)(b * Lc + l0 + qr)) * Dc + h * HDc + 16 * cf + r] = cacc[cf][i] * rinv[i];
        }
    }
}

extern "C" void kernel_launch(void* const* d_in, const int* in_sizes, int n_in,
                              void* d_out, int out_size, void* d_ws, size_t ws_size,
                              hipStream_t stream) {
    const float* hs = (const float*)d_in[0];
    const float* Wq = (const float*)d_in[1];
    const float* bq = (const float*)d_in[2];
    const float* Wk = (const float*)d_in[3];
    const float* bk = (const float*)d_in[4];
    const float* Wv = (const float*)d_in[5];
    const float* bv = (const float*)d_in[6];
    const float* Wd = (const float*)d_in[7];
    const float* bd = (const float*)d_in[8];
    const float* Eg = (const float*)d_in[9];

    const size_t NELEM = (size_t)Bc * Lc * Dc;          // 3,145,728
    ushort* qbf = (ushort*)d_ws;                         // bf16 head-major
    ushort* kbf = qbf + NELEM;
    ushort* vbf = kbf + NELEM;
    float*  ctx = (float*)(vbf + NELEM);                 // fp32 [B*L,768]
    ushort* Ebf = (ushort*)(ctx + NELEM);                // bf16 [2047,64]

    const int NE = (2 * 1024 - 1) * HDc;                 // 131,008

    cvt_bf16_k<<<dim3((NE + 255) / 256), dim3(256), 0, stream>>>(Eg, Ebf, NE);
    gemm64<1><<<dim3(12, 64, 3), dim3(256), 0, stream>>>(hs, Wq, Wk, Wv, bq, bk, bv,
                                                         qbf, kbf, vbf);
    attn_mfma<<<dim3(16, Hc, Bc), dim3(256), 0, stream>>>(qbf, kbf, vbf, Ebf, ctx);
    gemm64<0><<<dim3(12, 64, 1), dim3(256), 0, stream>>>(ctx, Wd, Wd, Wd, bd, bd, bd,
                                                         d_out, d_out, d_out);
}

// Round 3
// 364.776 us; speedup vs baseline: 3.4991x; 1.4018x over previous
//
#include <hip/hip_runtime.h>
#include <hip/hip_bf16.h>
#include <math.h>

typedef __bf16 bf16x8 __attribute__((ext_vector_type(8)));
typedef float f32x4 __attribute__((ext_vector_type(4)));

#define AS1 __attribute__((address_space(1)))
#define AS3 __attribute__((address_space(3)))
typedef AS1 const void gvoid;
typedef AS3 void svoid;

namespace {
constexpr int Bc = 4, Lc = 1024, Dc = 768, Hc = 12, HDc = 64;
constexpr int NKT = 24;          // K tiles: 768 / 32
}

static __device__ __forceinline__ ushort f2bf(float f) {
    __hip_bfloat16 h = __float2bfloat16(f);
    return *reinterpret_cast<ushort*>(&h);
}
static __device__ __forceinline__ float bf2f(ushort u) {
    __hip_bfloat16 h;
    *reinterpret_cast<ushort*>(&h) = u;
    return __bfloat162float(h);
}

// offset (ushort units) within an 8 KB [128 rows][32 cols] bf16 tile,
// paired-row XOR swizzle: 2 lanes/bank on ds_read_b128 (conflict-free min).
static __device__ __forceinline__ int sw_us(int row, int col) {
    int line = row >> 1;
    int slot = (((row & 1) << 2) + (col >> 3)) ^ (line & 7);
    return line * 64 + slot * 8 + (col & 7);
}

// ---------------- fp32 -> bf16 convert (dist_emb) --------------------------
__global__ void cvt_bf16_k(const float* __restrict__ in, ushort* __restrict__ out, int n) {
    int i = blockIdx.x * 256 + threadIdx.x;
    if (i < n) out[i] = f2bf(in[i]);
}

// ---------------- hs [4096,768] fp32 -> tiled swizzled hi/lo ---------------
__global__ __launch_bounds__(256) void prep_hs(const float* __restrict__ hs,
                                               ushort* __restrict__ oh,
                                               ushort* __restrict__ ol) {
    int i = blockIdx.x * 256 + threadIdx.x;      // 4096*96
    int m = i / 96, c8 = i % 96;
    const float* src = hs + (size_t)m * Dc + c8 * 8;
    float4 x0 = *(const float4*)src;
    float4 x1 = *(const float4*)(src + 4);
    float xs[8] = {x0.x, x0.y, x0.z, x0.w, x1.x, x1.y, x1.z, x1.w};
    ushort hi[8], lo[8];
#pragma unroll
    for (int j = 0; j < 8; ++j) {
        hi[j] = f2bf(xs[j]);
        lo[j] = f2bf(xs[j] - bf2f(hi[j]));
    }
    int col = c8 * 8, kt = col >> 5, kc = col & 31;
    int mt = m >> 7, row = m & 127;
    int off = (mt * NKT + kt) * 4096 + sw_us(row, kc);
    *(uint4*)(oh + off) = *(uint4*)hi;
    *(uint4*)(ol + off) = *(uint4*)lo;
}

// ---------------- W^T tiles: Wq|Wk|Wv packed [2304 n], Wd [768 n] ----------
__global__ __launch_bounds__(256) void prep_w(
    const float* __restrict__ Wq, const float* __restrict__ Wk,
    const float* __restrict__ Wv, const float* __restrict__ Wd,
    ushort* __restrict__ qkvh, ushort* __restrict__ qkvl,
    ushort* __restrict__ wdh, ushort* __restrict__ wdl) {
    int i = blockIdx.x * 256 + threadIdx.x;      // 768*384
    int k = i / 384, n8 = i % 384;
    int which = n8 / 96, nl = (n8 % 96) * 8;
    const float* W = which == 0 ? Wq : which == 1 ? Wk : which == 2 ? Wv : Wd;
    const float* src = W + (size_t)k * Dc + nl;
    float4 x0 = *(const float4*)src;
    float4 x1 = *(const float4*)(src + 4);
    float xs[8] = {x0.x, x0.y, x0.z, x0.w, x1.x, x1.y, x1.z, x1.w};
    int kt = k >> 5, kc = k & 31;
    ushort* dh = (which < 3) ? qkvh : wdh;
    ushort* dl = (which < 3) ? qkvl : wdl;
    int ngbase = (which < 3) ? which * Dc + nl : nl;
#pragma unroll
    for (int j = 0; j < 8; ++j) {
        float x = xs[j];
        ushort hi = f2bf(x);
        ushort lo = f2bf(x - bf2f(hi));
        int ng = ngbase + j;
        int nt = ng >> 7, row = ng & 127;
        int off = (nt * NKT + kt) * 4096 + sw_us(row, kc);
        dh[off] = hi;
        dl[off] = lo;
    }
}

// ---------------- split-bf16 MFMA GEMM: C = A@B (+bias) --------------------
// A tiles [mt][kt][128m][32k], B tiles [nt][kt][128n][32k] (pre-swizzled).
// MODE 0: bf16 head-major q/k/v out (+per-which bias). MODE 1: fp32 out.
template <int MODE>
__global__ __launch_bounds__(256) void gemm_split(
    const ushort* __restrict__ Ah, const ushort* __restrict__ Al,
    const ushort* __restrict__ Bh, const ushort* __restrict__ Bl,
    const float* __restrict__ b0, const float* __restrict__ b1,
    const float* __restrict__ b2,
    ushort* __restrict__ o0, ushort* __restrict__ o1, ushort* __restrict__ o2,
    float* __restrict__ of) {
    __shared__ uint4 lds4[4][512];   // Ah | Al | Bh | Bl, 8 KB each

    const int nt = blockIdx.x, mt = blockIdx.y;
    const int tid = threadIdx.x, w = tid >> 6, lane = tid & 63;
    const int wr = w >> 1, wc = w & 1, r = lane & 15, g = lane >> 4;

    const ushort* gsrc;
    if (w == 0)      gsrc = Ah + (size_t)mt * NKT * 4096;
    else if (w == 1) gsrc = Al + (size_t)mt * NKT * 4096;
    else if (w == 2) gsrc = Bh + (size_t)nt * NKT * 4096;
    else             gsrc = Bl + (size_t)nt * NKT * 4096;
    ushort* ldst = (ushort*)&lds4[w][0];

    f32x4 acc[4][4];
#pragma unroll
    for (int a = 0; a < 4; ++a)
#pragma unroll
        for (int b = 0; b < 4; ++b) acc[a][b] = (f32x4){0.f, 0.f, 0.f, 0.f};

    for (int kt = 0; kt < NKT; ++kt) {
        __syncthreads();
        const ushort* s = gsrc + kt * 4096 + lane * 8;
#pragma unroll
        for (int c = 0; c < 8; ++c)
            __builtin_amdgcn_global_load_lds((gvoid*)(s + c * 512),
                                             (svoid*)(ldst + c * 512), 16, 0, 0);
        __syncthreads();

        bf16x8 af[4][2];
#pragma unroll
        for (int mf = 0; mf < 4; ++mf) {
            int off = sw_us(wr * 64 + mf * 16 + r, g * 8);
            af[mf][0] = *(const bf16x8*)((const ushort*)&lds4[0][0] + off);
            af[mf][1] = *(const bf16x8*)((const ushort*)&lds4[1][0] + off);
        }
#pragma unroll
        for (int nf = 0; nf < 4; ++nf) {
            int off = sw_us(wc * 64 + nf * 16 + r, g * 8);
            bf16x8 bh = *(const bf16x8*)((const ushort*)&lds4[2][0] + off);
            bf16x8 bl = *(const bf16x8*)((const ushort*)&lds4[3][0] + off);
#pragma unroll
            for (int mf = 0; mf < 4; ++mf) {
                acc[mf][nf] = __builtin_amdgcn_mfma_f32_16x16x32_bf16(af[mf][0], bh, acc[mf][nf], 0, 0, 0);
                acc[mf][nf] = __builtin_amdgcn_mfma_f32_16x16x32_bf16(af[mf][0], bl, acc[mf][nf], 0, 0, 0);
                acc[mf][nf] = __builtin_amdgcn_mfma_f32_16x16x32_bf16(af[mf][1], bh, acc[mf][nf], 0, 0, 0);
            }
        }
    }

    if (MODE == 0) {
        const int which = nt / 6;
        const float* bias = which == 0 ? b0 : which == 1 ? b1 : b2;
        ushort* outp = which == 0 ? o0 : which == 1 ? o1 : o2;
        const int nbase = nt * 128 - which * Dc + wc * 64;
#pragma unroll
        for (int nf = 0; nf < 4; ++nf) {
            int nl = nbase + nf * 16 + r;
            float bb = bias[nl];
            int h = nl >> 6, d = nl & 63;
#pragma unroll
            for (int mf = 0; mf < 4; ++mf) {
                int mbase = mt * 128 + wr * 64 + mf * 16 + g * 4;
#pragma unroll
                for (int i = 0; i < 4; ++i) {
                    int m = mbase + i, bI = m >> 10, l = m & 1023;
                    outp[(((size_t)bI * Hc + h) * Lc + l) * HDc + d] =
                        f2bf(acc[mf][nf][i] + bb);
                }
            }
        }
    } else {
#pragma unroll
        for (int nf = 0; nf < 4; ++nf) {
            int n = nt * 128 + wc * 64 + nf * 16 + r;
            float bb = b0[n];
#pragma unroll
            for (int mf = 0; mf < 4; ++mf) {
                int mbase = mt * 128 + wr * 64 + mf * 16 + g * 4;
#pragma unroll
                for (int i = 0; i < 4; ++i) {
                    int m = mbase + i;
                    of[(size_t)m * Dc + n] = acc[mf][nf][i] + bb;
                }
            }
        }
    }
}

// ---------------- Fused relative-position attention (MFMA) -----------------
__global__ __launch_bounds__(256, 2) void attn_mfma(
    const ushort* __restrict__ qg, const ushort* __restrict__ kg,
    const ushort* __restrict__ vg, const ushort* __restrict__ Eb,
    ushort* __restrict__ ctxh, ushort* __restrict__ ctxl)
{
    const int b = blockIdx.z, h = blockIdx.y;
    const int l0 = blockIdx.x * 64;
    const size_t bh = (size_t)(b * Hc + h) * Lc * HDc;
    const ushort* qh = qg + bh;
    const ushort* kh = kg + bh;
    const ushort* vh = vg + bh;

    __shared__ ushort sK[64][72];
    __shared__ ushort sVt[64][72];
    __shared__ ushort sEP[128 * 72];
    __shared__ ushort sQE[64][132];
    __shared__ ushort sKE[64][132];

    const int tid = threadIdx.x;
    const int lane = tid & 63;
    const int w = tid >> 6;
    const int g = lane >> 4;
    const int r = lane & 15;

    bf16x8 qf0, qf1;
    {
        const ushort* qrow = qh + (size_t)(l0 + 16 * w + r) * 64;
        qf0 = *reinterpret_cast<const bf16x8*>(qrow + g * 8);
        qf1 = *reinterpret_cast<const bf16x8*>(qrow + 32 + g * 8);
    }

    f32x4 cacc[4];
#pragma unroll
    for (int cf = 0; cf < 4; ++cf) cacc[cf] = (f32x4){0.f, 0.f, 0.f, 0.f};
    float mrun[4], lrun[4];
#pragma unroll
    for (int i = 0; i < 4; ++i) { mrun[i] = -1e30f; lrun[i] = 0.f; }

    for (int r0 = 0; r0 < Lc; r0 += 64) {
        __syncthreads();
#pragma unroll
        for (int c = tid; c < 512; c += 256) {
            int row = c >> 3, seg = c & 7;
            *reinterpret_cast<uint4*>(&sK[row][seg * 8]) =
                *reinterpret_cast<const uint4*>(kh + (size_t)(r0 + row) * 64 + seg * 8);
        }
        {
            int row = tid & 63, dseg = tid >> 6;
            const ushort* vrow = vh + (size_t)(r0 + row) * 64 + dseg * 16;
            uint4 a0 = *reinterpret_cast<const uint4*>(vrow);
            uint4 a1 = *reinterpret_cast<const uint4*>(vrow + 8);
            const ushort* t0 = reinterpret_cast<const ushort*>(&a0);
            const ushort* t1 = reinterpret_cast<const ushort*>(&a1);
#pragma unroll
            for (int j = 0; j < 8; ++j) sVt[dseg * 16 + j][row] = t0[j];
#pragma unroll
            for (int j = 0; j < 8; ++j) sVt[dseg * 16 + 8 + j][row] = t1[j];
        }
        const int jb = l0 - r0 + 960;
#pragma unroll
        for (int c = tid; c < 1024; c += 256) {
            int row = c >> 3, seg = c & 7;
            uint4 val;
            if (row < 127)
                val = *reinterpret_cast<const uint4*>(Eb + (size_t)(jb + row) * 64 + seg * 8);
            else
                val = make_uint4(0, 0, 0, 0);
            *reinterpret_cast<uint4*>(&sEP[row * 72 + seg * 8]) = val;
        }
        __syncthreads();

        f32x4 S[4];
#pragma unroll
        for (int cf = 0; cf < 4; ++cf) {
            f32x4 acc = (f32x4){0.f, 0.f, 0.f, 0.f};
            bf16x8 kf0 = *reinterpret_cast<const bf16x8*>(&sK[16 * cf + r][g * 8]);
            bf16x8 kf1 = *reinterpret_cast<const bf16x8*>(&sK[16 * cf + r][32 + g * 8]);
            acc = __builtin_amdgcn_mfma_f32_16x16x32_bf16(qf0, kf0, acc, 0, 0, 0);
            acc = __builtin_amdgcn_mfma_f32_16x16x32_bf16(qf1, kf1, acc, 0, 0, 0);
            S[cf] = acc;
        }
        bf16x8 kaf0 = *reinterpret_cast<const bf16x8*>(&sK[16 * w + r][g * 8]);
        bf16x8 kaf1 = *reinterpret_cast<const bf16x8*>(&sK[16 * w + r][32 + g * 8]);
#pragma unroll
        for (int cf = 0; cf < 8; ++cf) {
            bf16x8 ef0 = *reinterpret_cast<const bf16x8*>(&sEP[(16 * cf + r) * 72 + g * 8]);
            bf16x8 ef1 = *reinterpret_cast<const bf16x8*>(&sEP[(16 * cf + r) * 72 + 32 + g * 8]);
            f32x4 aq = (f32x4){0.f, 0.f, 0.f, 0.f};
            f32x4 ak = (f32x4){0.f, 0.f, 0.f, 0.f};
            aq = __builtin_amdgcn_mfma_f32_16x16x32_bf16(qf0, ef0, aq, 0, 0, 0);
            aq = __builtin_amdgcn_mfma_f32_16x16x32_bf16(qf1, ef1, aq, 0, 0, 0);
            ak = __builtin_amdgcn_mfma_f32_16x16x32_bf16(kaf0, ef0, ak, 0, 0, 0);
            ak = __builtin_amdgcn_mfma_f32_16x16x32_bf16(kaf1, ef1, ak, 0, 0, 0);
#pragma unroll
            for (int i = 0; i < 4; ++i) {
                sQE[16 * w + 4 * g + i][16 * cf + r] = f2bf(aq[i]);
                sKE[16 * w + 4 * g + i][16 * cf + r] = f2bf(ak[i]);
            }
        }
        __syncthreads();

        float p[4][4];
#pragma unroll
        for (int cf = 0; cf < 4; ++cf) {
#pragma unroll
            for (int i = 0; i < 4; ++i) {
                int qr = 16 * w + 4 * g + i;
                int kc = 16 * cf + r;
                int col = qr - kc + 63;
                p[cf][i] = (S[cf][i] + bf2f(sQE[qr][col]) + bf2f(sKE[kc][col])) * 0.125f;
            }
        }
#pragma unroll
        for (int i = 0; i < 4; ++i) {
            float m0 = fmaxf(fmaxf(p[0][i], p[1][i]), fmaxf(p[2][i], p[3][i]));
#pragma unroll
            for (int off = 1; off < 16; off <<= 1) m0 = fmaxf(m0, __shfl_xor(m0, off));
            float mn = fmaxf(mrun[i], m0);
            float sc = __expf(mrun[i] - mn);
            mrun[i] = mn;
            float rsum = 0.f;
#pragma unroll
            for (int cf = 0; cf < 4; ++cf) {
                float e = __expf(p[cf][i] - mn);
                p[cf][i] = e;
                rsum += e;
            }
#pragma unroll
            for (int off = 1; off < 16; off <<= 1) rsum += __shfl_xor(rsum, off);
            lrun[i] = lrun[i] * sc + rsum;
#pragma unroll
            for (int cf = 0; cf < 4; ++cf) cacc[cf][i] *= sc;
        }
#pragma unroll
        for (int cf = 0; cf < 4; ++cf)
#pragma unroll
            for (int i = 0; i < 4; ++i)
                sEP[(16 * w + 4 * g + i) * 72 + 16 * cf + r] = f2bf(p[cf][i]);
        __syncthreads();

        bf16x8 pf0 = *reinterpret_cast<const bf16x8*>(&sEP[(16 * w + r) * 72 + g * 8]);
        bf16x8 pf1 = *reinterpret_cast<const bf16x8*>(&sEP[(16 * w + r) * 72 + 32 + g * 8]);
#pragma unroll
        for (int cf = 0; cf < 4; ++cf) {
            bf16x8 vf0 = *reinterpret_cast<const bf16x8*>(&sVt[16 * cf + r][g * 8]);
            bf16x8 vf1 = *reinterpret_cast<const bf16x8*>(&sVt[16 * cf + r][32 + g * 8]);
            cacc[cf] = __builtin_amdgcn_mfma_f32_16x16x32_bf16(pf0, vf0, cacc[cf], 0, 0, 0);
            cacc[cf] = __builtin_amdgcn_mfma_f32_16x16x32_bf16(pf1, vf1, cacc[cf], 0, 0, 0);
        }
    }

    // epilogue: write ctx as swizzled hi/lo A-tiles for the output GEMM
    float rinv[4];
#pragma unroll
    for (int i = 0; i < 4; ++i) rinv[i] = 1.0f / lrun[i];
#pragma unroll
    for (int cf = 0; cf < 4; ++cf) {
#pragma unroll
        for (int i = 0; i < 4; ++i) {
            int qr = 16 * w + 4 * g + i;
            float val = cacc[cf][i] * rinv[i];
            ushort hi = f2bf(val);
            ushort lo = f2bf(val - bf2f(hi));
            int m = b * Lc + l0 + qr;
            int c = h * HDc + 16 * cf + r;
            int off = ((m >> 7) * NKT + (c >> 5)) * 4096 + sw_us(m & 127, c & 31);
            ctxh[off] = hi;
            ctxl[off] = lo;
        }
    }
}

extern "C" void kernel_launch(void* const* d_in, const int* in_sizes, int n_in,
                              void* d_out, int out_size, void* d_ws, size_t ws_size,
                              hipStream_t stream) {
    const float* hs = (const float*)d_in[0];
    const float* Wq = (const float*)d_in[1];
    const float* bq = (const float*)d_in[2];
    const float* Wk = (const float*)d_in[3];
    const float* bk = (const float*)d_in[4];
    const float* Wv = (const float*)d_in[5];
    const float* bv = (const float*)d_in[6];
    const float* Wd = (const float*)d_in[7];
    const float* bd = (const float*)d_in[8];
    const float* Eg = (const float*)d_in[9];

    const size_t N = (size_t)Bc * Lc * Dc;               // 3,145,728
    ushort* p = (ushort*)d_ws;
    ushort* qbf   = p;               p += N;
    ushort* kbf   = p;               p += N;
    ushort* vbf   = p;               p += N;
    ushort* hsh   = p;               p += N;             // aliased: ctx_hi after QKV
    ushort* hsl   = p;               p += N;             // aliased: ctx_lo
    ushort* wqkvh = p;               p += (size_t)2304 * 768;
    ushort* wqkvl = p;               p += (size_t)2304 * 768;
    ushort* wdh   = p;               p += (size_t)768 * 768;
    ushort* wdl   = p;               p += (size_t)768 * 768;
    ushort* Ebf   = p;

    const int NE = (2 * 1024 - 1) * HDc;                 // 131,008

    cvt_bf16_k<<<dim3(512), dim3(256), 0, stream>>>(Eg, Ebf, NE);
    prep_hs<<<dim3(1536), dim3(256), 0, stream>>>(hs, hsh, hsl);
    prep_w<<<dim3(1152), dim3(256), 0, stream>>>(Wq, Wk, Wv, Wd, wqkvh, wqkvl, wdh, wdl);

    gemm_split<0><<<dim3(18, 32), dim3(256), 0, stream>>>(
        hsh, hsl, wqkvh, wqkvl, bq, bk, bv, qbf, kbf, vbf, nullptr);

    attn_mfma<<<dim3(16, Hc, Bc), dim3(256), 0, stream>>>(
        qbf, kbf, vbf, Ebf, hsh, hsl);                   // ctx overwrites hs tiles

    gemm_split<1><<<dim3(6, 32), dim3(256), 0, stream>>>(
        hsh, hsl, wdh, wdl, bd, bd, bd, nullptr, nullptr, nullptr, (float*)d_out);
}

// Round 5
// 358.217 us; speedup vs baseline: 3.5632x; 1.0183x over previous
//
#include <hip/hip_runtime.h>
#include <hip/hip_bf16.h>
#include <math.h>

typedef __bf16 bf16x8 __attribute__((ext_vector_type(8)));
typedef float f32x4 __attribute__((ext_vector_type(4)));

#define AS1 __attribute__((address_space(1)))
#define AS3 __attribute__((address_space(3)))
typedef AS1 const void gvoid;
typedef AS3 void svoid;

namespace {
constexpr int Bc = 4, Lc = 1024, Dc = 768, Hc = 12, HDc = 64;
constexpr int NKT = 24;          // K tiles: 768 / 32
}

static __device__ __forceinline__ ushort f2bf(float f) {
    __hip_bfloat16 h = __float2bfloat16(f);
    return *reinterpret_cast<ushort*>(&h);
}
static __device__ __forceinline__ float bf2f(ushort u) {
    __hip_bfloat16 h;
    *reinterpret_cast<ushort*>(&h) = u;
    return __bfloat162float(h);
}

// offset (ushort units) within an 8 KB [128 rows][32 cols] bf16 tile,
// paired-row XOR swizzle: 2 lanes/bank on ds_read_b128 (conflict-free min).
static __device__ __forceinline__ int sw_us(int row, int col) {
    int line = row >> 1;
    int slot = (((row & 1) << 2) + (col >> 3)) ^ (line & 7);
    return line * 64 + slot * 8 + (col & 7);
}

// ---------------- fp32 -> bf16 convert (dist_emb) --------------------------
__global__ void cvt_bf16_k(const float* __restrict__ in, ushort* __restrict__ out, int n) {
    int i = blockIdx.x * 256 + threadIdx.x;
    if (i < n) out[i] = f2bf(in[i]);
}

// ---------------- hs [4096,768] fp32 -> tiled swizzled hi/lo ---------------
__global__ __launch_bounds__(256) void prep_hs(const float* __restrict__ hs,
                                               ushort* __restrict__ oh,
                                               ushort* __restrict__ ol) {
    int i = blockIdx.x * 256 + threadIdx.x;      // 4096*96
    int m = i / 96, c8 = i % 96;
    const float* src = hs + (size_t)m * Dc + c8 * 8;
    float4 x0 = *(const float4*)src;
    float4 x1 = *(const float4*)(src + 4);
    float xs[8] = {x0.x, x0.y, x0.z, x0.w, x1.x, x1.y, x1.z, x1.w};
    ushort hi[8], lo[8];
#pragma unroll
    for (int j = 0; j < 8; ++j) {
        hi[j] = f2bf(xs[j]);
        lo[j] = f2bf(xs[j] - bf2f(hi[j]));
    }
    int col = c8 * 8, kt = col >> 5, kc = col & 31;
    int mt = m >> 7, row = m & 127;
    int off = (mt * NKT + kt) * 4096 + sw_us(row, kc);
    *(uint4*)(oh + off) = *(uint4*)hi;
    *(uint4*)(ol + off) = *(uint4*)lo;
}

// ---------------- W^T tiles: Wq|Wk|Wv packed [2304 n], Wd [768 n] ----------
__global__ __launch_bounds__(256) void prep_w(
    const float* __restrict__ Wq, const float* __restrict__ Wk,
    const float* __restrict__ Wv, const float* __restrict__ Wd,
    ushort* __restrict__ qkvh, ushort* __restrict__ qkvl,
    ushort* __restrict__ wdh, ushort* __restrict__ wdl) {
    int i = blockIdx.x * 256 + threadIdx.x;      // 768*384
    int k = i / 384, n8 = i % 384;
    int which = n8 / 96, nl = (n8 % 96) * 8;
    const float* W = which == 0 ? Wq : which == 1 ? Wk : which == 2 ? Wv : Wd;
    const float* src = W + (size_t)k * Dc + nl;
    float4 x0 = *(const float4*)src;
    float4 x1 = *(const float4*)(src + 4);
    float xs[8] = {x0.x, x0.y, x0.z, x0.w, x1.x, x1.y, x1.z, x1.w};
    int kt = k >> 5, kc = k & 31;
    ushort* dh = (which < 3) ? qkvh : wdh;
    ushort* dl = (which < 3) ? qkvl : wdl;
    int ngbase = (which < 3) ? which * Dc + nl : nl;
#pragma unroll
    for (int j = 0; j < 8; ++j) {
        float x = xs[j];
        ushort hi = f2bf(x);
        ushort lo = f2bf(x - bf2f(hi));
        int ng = ngbase + j;
        int nt = ng >> 7, row = ng & 127;
        int off = (nt * NKT + kt) * 4096 + sw_us(row, kc);
        dh[off] = hi;
        dl[off] = lo;
    }
}

// ---------------- split-bf16 MFMA GEMM: C = A@B (+bias) --------------------
// MODE 0: bf16 out — q/k head-major [b,h,l,d], v TRANSPOSED [b,h,d,l].
// MODE 1: fp32 out plain [M,768].
template <int MODE>
__global__ __launch_bounds__(256) void gemm_split(
    const ushort* __restrict__ Ah, const ushort* __restrict__ Al,
    const ushort* __restrict__ Bh, const ushort* __restrict__ Bl,
    const float* __restrict__ b0, const float* __restrict__ b1,
    const float* __restrict__ b2,
    ushort* __restrict__ o0, ushort* __restrict__ o1, ushort* __restrict__ o2,
    float* __restrict__ of) {
    __shared__ uint4 lds4[4][512];   // Ah | Al | Bh | Bl, 8 KB each

    const int nt = blockIdx.x, mt = blockIdx.y;
    const int tid = threadIdx.x, w = tid >> 6, lane = tid & 63;
    const int wr = w >> 1, wc = w & 1, r = lane & 15, g = lane >> 4;

    const ushort* gsrc;
    if (w == 0)      gsrc = Ah + (size_t)mt * NKT * 4096;
    else if (w == 1) gsrc = Al + (size_t)mt * NKT * 4096;
    else if (w == 2) gsrc = Bh + (size_t)nt * NKT * 4096;
    else             gsrc = Bl + (size_t)nt * NKT * 4096;
    ushort* ldst = (ushort*)&lds4[w][0];

    f32x4 acc[4][4];
#pragma unroll
    for (int a = 0; a < 4; ++a)
#pragma unroll
        for (int b = 0; b < 4; ++b) acc[a][b] = (f32x4){0.f, 0.f, 0.f, 0.f};

    for (int kt = 0; kt < NKT; ++kt) {
        __syncthreads();
        const ushort* s = gsrc + kt * 4096 + lane * 8;
#pragma unroll
        for (int c = 0; c < 8; ++c)
            __builtin_amdgcn_global_load_lds((gvoid*)(s + c * 512),
                                             (svoid*)(ldst + c * 512), 16, 0, 0);
        __syncthreads();

        bf16x8 af[4][2];
#pragma unroll
        for (int mf = 0; mf < 4; ++mf) {
            int off = sw_us(wr * 64 + mf * 16 + r, g * 8);
            af[mf][0] = *(const bf16x8*)((const ushort*)&lds4[0][0] + off);
            af[mf][1] = *(const bf16x8*)((const ushort*)&lds4[1][0] + off);
        }
#pragma unroll
        for (int nf = 0; nf < 4; ++nf) {
            int off = sw_us(wc * 64 + nf * 16 + r, g * 8);
            bf16x8 bh = *(const bf16x8*)((const ushort*)&lds4[2][0] + off);
            bf16x8 bl = *(const bf16x8*)((const ushort*)&lds4[3][0] + off);
#pragma unroll
            for (int mf = 0; mf < 4; ++mf) {
                acc[mf][nf] = __builtin_amdgcn_mfma_f32_16x16x32_bf16(af[mf][0], bh, acc[mf][nf], 0, 0, 0);
                acc[mf][nf] = __builtin_amdgcn_mfma_f32_16x16x32_bf16(af[mf][0], bl, acc[mf][nf], 0, 0, 0);
                acc[mf][nf] = __builtin_amdgcn_mfma_f32_16x16x32_bf16(af[mf][1], bh, acc[mf][nf], 0, 0, 0);
            }
        }
    }

    if (MODE == 0) {
        const int which = nt / 6;
        const float* bias = which == 0 ? b0 : which == 1 ? b1 : b2;
        ushort* outp = which == 0 ? o0 : which == 1 ? o1 : o2;
        const int nbase = nt * 128 - which * Dc + wc * 64;
        if (which < 2) {
#pragma unroll
            for (int nf = 0; nf < 4; ++nf) {
                int nl = nbase + nf * 16 + r;
                float bb = bias[nl];
                int h = nl >> 6, d = nl & 63;
#pragma unroll
                for (int mf = 0; mf < 4; ++mf) {
                    int mbase = mt * 128 + wr * 64 + mf * 16 + g * 4;
#pragma unroll
                    for (int i = 0; i < 4; ++i) {
                        int m = mbase + i, bI = m >> 10, l = m & 1023;
                        outp[(((size_t)bI * Hc + h) * Lc + l) * HDc + d] =
                            f2bf(acc[mf][nf][i] + bb);
                    }
                }
            }
        } else {   // V: transposed [b, h, d, l], vectorized along l
#pragma unroll
            for (int nf = 0; nf < 4; ++nf) {
                int nl = nbase + nf * 16 + r;
                float bb = bias[nl];
                int h = nl >> 6, d = nl & 63;
#pragma unroll
                for (int mf = 0; mf < 4; ++mf) {
                    int mbase = mt * 128 + wr * 64 + mf * 16 + g * 4;
                    int bI = mbase >> 10, l = mbase & 1023;
                    ushort4 c;
                    c.x = f2bf(acc[mf][nf][0] + bb);
                    c.y = f2bf(acc[mf][nf][1] + bb);
                    c.z = f2bf(acc[mf][nf][2] + bb);
                    c.w = f2bf(acc[mf][nf][3] + bb);
                    *(ushort4*)&outp[((size_t)(bI * Hc + h) * HDc + d) * Lc + l] = c;
                }
            }
        }
    } else {
#pragma unroll
        for (int nf = 0; nf < 4; ++nf) {
            int n = nt * 128 + wc * 64 + nf * 16 + r;
            float bb = b0[n];
#pragma unroll
            for (int mf = 0; mf < 4; ++mf) {
                int mbase = mt * 128 + wr * 64 + mf * 16 + g * 4;
#pragma unroll
                for (int i = 0; i < 4; ++i) {
                    int m = mbase + i;
                    of[(size_t)m * Dc + n] = acc[mf][nf][i] + bb;
                }
            }
        }
    }
}

// ---------------- Fused relative-position attention (MFMA) -----------------
// Round-3 structure (proven post-timing stable) + V^T global staging + setprio.
// grid (16, H, B), 4 waves. scores[l][r] = (q.k + q.E_j + k.E_j)/8, j=l-r+1023.
__global__ __launch_bounds__(256, 2) void attn_mfma(
    const ushort* __restrict__ qg, const ushort* __restrict__ kg,
    const ushort* __restrict__ vtg, const ushort* __restrict__ Eb,
    ushort* __restrict__ ctxh, ushort* __restrict__ ctxl)
{
    const int b = blockIdx.z, h = blockIdx.y;
    const int l0 = blockIdx.x * 64;
    const size_t bh = (size_t)(b * Hc + h) * Lc * HDc;
    const ushort* qh = qg + bh;
    const ushort* kh = kg + bh;
    const ushort* vth = vtg + bh;     // [d][l] rows stride Lc

    __shared__ ushort sK[64][72];       //  9216 B
    __shared__ ushort sVt[64][72];      //  9216 B  V^T tile [dim][key]
    __shared__ ushort sEP[128 * 72];    // 18432 B  E band / P probs
    __shared__ ushort sQE[64][132];     // 16896 B
    __shared__ ushort sKE[64][132];     // 16896 B

    const int tid = threadIdx.x;
    const int lane = tid & 63;
    const int w = tid >> 6;
    const int g = lane >> 4;
    const int r = lane & 15;

    bf16x8 qf0, qf1;
    {
        const ushort* qrow = qh + (size_t)(l0 + 16 * w + r) * 64;
        qf0 = *reinterpret_cast<const bf16x8*>(qrow + g * 8);
        qf1 = *reinterpret_cast<const bf16x8*>(qrow + 32 + g * 8);
    }

    f32x4 cacc[4];
#pragma unroll
    for (int cf = 0; cf < 4; ++cf) cacc[cf] = (f32x4){0.f, 0.f, 0.f, 0.f};
    float mrun[4], lrun[4];
#pragma unroll
    for (int i = 0; i < 4; ++i) { mrun[i] = -1e30f; lrun[i] = 0.f; }

    for (int r0 = 0; r0 < Lc; r0 += 64) {
        __syncthreads();                       // prev iter fully consumed
        // ---- phase A: stage K, V^T, E band
#pragma unroll
        for (int i = 0; i < 2; ++i) {
            int idx = tid + i * 256;
            int row = idx >> 3, seg = idx & 7;
            *reinterpret_cast<uint4*>(&sK[row][seg * 8]) =
                *reinterpret_cast<const uint4*>(kh + (size_t)(r0 + row) * 64 + seg * 8);
            *reinterpret_cast<uint4*>(&sVt[row][seg * 8]) =
                *reinterpret_cast<const uint4*>(vth + (size_t)row * Lc + r0 + seg * 8);
        }
        const int jb = l0 - r0 + 960;          // rows jb..jb+126 valid in E
#pragma unroll
        for (int c = tid; c < 1024; c += 256) {
            int row = c >> 3, seg = c & 7;
            uint4 val;
            if (row < 127)
                val = *reinterpret_cast<const uint4*>(Eb + (size_t)(jb + row) * 64 + seg * 8);
            else
                val = make_uint4(0, 0, 0, 0);
            *reinterpret_cast<uint4*>(&sEP[row * 72 + seg * 8]) = val;
        }
        __syncthreads();                       // A -> B

        // ---- phase B: QK^T, QE^T, KE^T via MFMA
        __builtin_amdgcn_s_setprio(1);
        f32x4 S[4];
#pragma unroll
        for (int cf = 0; cf < 4; ++cf) {
            f32x4 acc = (f32x4){0.f, 0.f, 0.f, 0.f};
            bf16x8 kf0 = *reinterpret_cast<const bf16x8*>(&sK[16 * cf + r][g * 8]);
            bf16x8 kf1 = *reinterpret_cast<const bf16x8*>(&sK[16 * cf + r][32 + g * 8]);
            acc = __builtin_amdgcn_mfma_f32_16x16x32_bf16(qf0, kf0, acc, 0, 0, 0);
            acc = __builtin_amdgcn_mfma_f32_16x16x32_bf16(qf1, kf1, acc, 0, 0, 0);
            S[cf] = acc;
        }
        bf16x8 kaf0 = *reinterpret_cast<const bf16x8*>(&sK[16 * w + r][g * 8]);
        bf16x8 kaf1 = *reinterpret_cast<const bf16x8*>(&sK[16 * w + r][32 + g * 8]);
#pragma unroll
        for (int cf = 0; cf < 8; ++cf) {
            bf16x8 ef0 = *reinterpret_cast<const bf16x8*>(&sEP[(16 * cf + r) * 72 + g * 8]);
            bf16x8 ef1 = *reinterpret_cast<const bf16x8*>(&sEP[(16 * cf + r) * 72 + 32 + g * 8]);
            f32x4 aq = (f32x4){0.f, 0.f, 0.f, 0.f};
            f32x4 ak = (f32x4){0.f, 0.f, 0.f, 0.f};
            aq = __builtin_amdgcn_mfma_f32_16x16x32_bf16(qf0, ef0, aq, 0, 0, 0);
            aq = __builtin_amdgcn_mfma_f32_16x16x32_bf16(qf1, ef1, aq, 0, 0, 0);
            ak = __builtin_amdgcn_mfma_f32_16x16x32_bf16(kaf0, ef0, ak, 0, 0, 0);
            ak = __builtin_amdgcn_mfma_f32_16x16x32_bf16(kaf1, ef1, ak, 0, 0, 0);
#pragma unroll
            for (int i = 0; i < 4; ++i) {
                sQE[16 * w + 4 * g + i][16 * cf + r] = f2bf(aq[i]);
                sKE[16 * w + 4 * g + i][16 * cf + r] = f2bf(ak[i]);
            }
        }
        __builtin_amdgcn_s_setprio(0);
        __syncthreads();                       // B -> C

        // ---- phase C: assemble S + online softmax (C-frag layout)
        float p[4][4];
#pragma unroll
        for (int cf = 0; cf < 4; ++cf) {
#pragma unroll
            for (int i = 0; i < 4; ++i) {
                int qr = 16 * w + 4 * g + i;
                int kc = 16 * cf + r;
                int col = qr - kc + 63;
                p[cf][i] = (S[cf][i] + bf2f(sQE[qr][col]) + bf2f(sKE[kc][col])) * 0.125f;
            }
        }
#pragma unroll
        for (int i = 0; i < 4; ++i) {
            float m0 = fmaxf(fmaxf(p[0][i], p[1][i]), fmaxf(p[2][i], p[3][i]));
#pragma unroll
            for (int off = 1; off < 16; off <<= 1) m0 = fmaxf(m0, __shfl_xor(m0, off));
            float mn = fmaxf(mrun[i], m0);
            float sc = __expf(mrun[i] - mn);
            mrun[i] = mn;
            float rsum = 0.f;
#pragma unroll
            for (int cf = 0; cf < 4; ++cf) {
                float e = __expf(p[cf][i] - mn);
                p[cf][i] = e;
                rsum += e;
            }
#pragma unroll
            for (int off = 1; off < 16; off <<= 1) rsum += __shfl_xor(rsum, off);
            lrun[i] = lrun[i] * sc + rsum;
#pragma unroll
            for (int cf = 0; cf < 4; ++cf) cacc[cf][i] *= sc;
        }
        // write P (bf16) into sEP region (E already consumed)
#pragma unroll
        for (int cf = 0; cf < 4; ++cf)
#pragma unroll
            for (int i = 0; i < 4; ++i)
                sEP[(16 * w + 4 * g + i) * 72 + 16 * cf + r] = f2bf(p[cf][i]);
        __syncthreads();                       // C -> D

        // ---- phase D: PV
        __builtin_amdgcn_s_setprio(1);
        bf16x8 pf0 = *reinterpret_cast<const bf16x8*>(&sEP[(16 * w + r) * 72 + g * 8]);
        bf16x8 pf1 = *reinterpret_cast<const bf16x8*>(&sEP[(16 * w + r) * 72 + 32 + g * 8]);
#pragma unroll
        for (int cf = 0; cf < 4; ++cf) {
            bf16x8 vf0 = *reinterpret_cast<const bf16x8*>(&sVt[16 * cf + r][g * 8]);
            bf16x8 vf1 = *reinterpret_cast<const bf16x8*>(&sVt[16 * cf + r][32 + g * 8]);
            cacc[cf] = __builtin_amdgcn_mfma_f32_16x16x32_bf16(pf0, vf0, cacc[cf], 0, 0, 0);
            cacc[cf] = __builtin_amdgcn_mfma_f32_16x16x32_bf16(pf1, vf1, cacc[cf], 0, 0, 0);
        }
        __builtin_amdgcn_s_setprio(0);
    }

    // epilogue: write ctx as swizzled hi/lo A-tiles for the output GEMM
    float rinv[4];
#pragma unroll
    for (int i = 0; i < 4; ++i) rinv[i] = 1.0f / lrun[i];
#pragma unroll
    for (int cf = 0; cf < 4; ++cf) {
#pragma unroll
        for (int i = 0; i < 4; ++i) {
            int qr = 16 * w + 4 * g + i;
            float val = cacc[cf][i] * rinv[i];
            ushort hi = f2bf(val);
            ushort lo = f2bf(val - bf2f(hi));
            int m = b * Lc + l0 + qr;
            int c = h * HDc + 16 * cf + r;
            int off = ((m >> 7) * NKT + (c >> 5)) * 4096 + sw_us(m & 127, c & 31);
            ctxh[off] = hi;
            ctxl[off] = lo;
        }
    }
}

extern "C" void kernel_launch(void* const* d_in, const int* in_sizes, int n_in,
                              void* d_out, int out_size, void* d_ws, size_t ws_size,
                              hipStream_t stream) {
    const float* hs = (const float*)d_in[0];
    const float* Wq = (const float*)d_in[1];
    const float* bq = (const float*)d_in[2];
    const float* Wk = (const float*)d_in[3];
    const float* bk = (const float*)d_in[4];
    const float* Wv = (const float*)d_in[5];
    const float* bv = (const float*)d_in[6];
    const float* Wd = (const float*)d_in[7];
    const float* bd = (const float*)d_in[8];
    const float* Eg = (const float*)d_in[9];

    const size_t N = (size_t)Bc * Lc * Dc;               // 3,145,728
    ushort* p = (ushort*)d_ws;
    ushort* qbf   = p;               p += N;
    ushort* kbf   = p;               p += N;
    ushort* vbf   = p;               p += N;             // V^T [b,h,d,l]
    ushort* hsh   = p;               p += N;             // aliased: ctx_hi after QKV
    ushort* hsl   = p;               p += N;             // aliased: ctx_lo
    ushort* wqkvh = p;               p += (size_t)2304 * 768;
    ushort* wqkvl = p;               p += (size_t)2304 * 768;
    ushort* wdh   = p;               p += (size_t)768 * 768;
    ushort* wdl   = p;               p += (size_t)768 * 768;
    ushort* Ebf   = p;

    const int NE = (2 * 1024 - 1) * HDc;                 // 131,008

    cvt_bf16_k<<<dim3(512), dim3(256), 0, stream>>>(Eg, Ebf, NE);
    prep_hs<<<dim3(1536), dim3(256), 0, stream>>>(hs, hsh, hsl);
    prep_w<<<dim3(1152), dim3(256), 0, stream>>>(Wq, Wk, Wv, Wd, wqkvh, wqkvl, wdh, wdl);

    gemm_split<0><<<dim3(18, 32), dim3(256), 0, stream>>>(
        hsh, hsl, wqkvh, wqkvl, bq, bk, bv, qbf, kbf, vbf, nullptr);

    attn_mfma<<<dim3(16, Hc, Bc), dim3(256), 0, stream>>>(
        qbf, kbf, vbf, Ebf, hsh, hsl);                   // ctx overwrites hs tiles

    gemm_split<1><<<dim3(6, 32), dim3(256), 0, stream>>>(
        hsh, hsl, wdh, wdl, bd, bd, bd, nullptr, nullptr, nullptr, (float*)d_out);
}